// Round 1
// baseline (517.378 us; speedup 1.0000x reference)
//
#include <hip/hip_runtime.h>
#include <math.h>

// Problem constants
#define B_ 4
#define L_ 4096
#define E_ 1024
#define H_ 16
#define D_ 64
#define N_ 64          // B*H
#define D2_ 128        // 2*D
#define EPS_ 1e-6f

#define KV_ELEMS (N_ * D2_ * D_)   // 524288
#define KS_ELEMS (N_ * D2_)        // 8192

#define TL_ 8  // l-rows staged per LDS tile in phase1

// ---------------------------------------------------------------------------
// Phase 1: partial kv = k_^T v  and ksum = sum_l k_  per (chunk, head)
// grid: chunks*64 blocks, 256 threads. bid&63 = head n, bid>>6 = chunk.
// ---------------------------------------------------------------------------
__global__ __launch_bounds__(256) void phase1_kernel(
    const float* __restrict__ k, const float* __restrict__ v,
    const float* __restrict__ mask,
    float* __restrict__ part_kv, float* __restrict__ part_ks, int lchunk) {
  __shared__ float ksh[TL_][D2_];  // k_ rows: [0..63]=s-part, [64..127]=c-part
  __shared__ float vsh[TL_][D_];

  const int bid = blockIdx.x;
  const int n = bid & 63;
  const int ch = bid >> 6;
  const int b = n >> 4;
  const int h = n & 15;
  const int t = threadIdx.x;
  const int m = t & 63;   // output column (v dim)
  const int g = t >> 6;   // wave id -> owns d in [g*32, g*32+32)

  float acc[32];
#pragma unroll
  for (int i = 0; i < 32; ++i) acc[i] = 0.f;
  float ksacc = 0.f;

  const int lbase = ch * lchunk;
  const int ntiles = lchunk / TL_;
  const float angscale = 0.5f * (float)M_PI / (float)L_;

  for (int lt = 0; lt < ntiles; ++lt) {
    const int l0 = lbase + lt * TL_;
    __syncthreads();  // protect LDS from previous iteration's readers
#pragma unroll
    for (int r = 0; r < 2; ++r) {
      const int e = t + 256 * r;
      const int tl = e >> 6;
      const int col = e & 63;
      const int l = l0 + tl;
      const float mk = mask[b * L_ + l];
      float kr = k[(size_t)(b * L_ + l) * E_ + h * 64 + col];
      kr = fmaxf(kr, 0.f) * mk;
      const float ang = (float)(l + 1) * angscale;
      ksh[tl][col] = kr * __sinf(ang);
      ksh[tl][col + 64] = kr * __cosf(ang);
      vsh[tl][col] = v[(size_t)(b * L_ + l) * E_ + h * 64 + col] * mk;
    }
    __syncthreads();
#pragma unroll
    for (int tl = 0; tl < TL_; ++tl) {
      const float vv = vsh[tl][m];
      const float4* kr4 = (const float4*)&ksh[tl][g * 32];
#pragma unroll
      for (int i = 0; i < 8; ++i) {
        const float4 kk = kr4[i];  // broadcast read (all lanes same addr)
        acc[4 * i + 0] = fmaf(kk.x, vv, acc[4 * i + 0]);
        acc[4 * i + 1] = fmaf(kk.y, vv, acc[4 * i + 1]);
        acc[4 * i + 2] = fmaf(kk.z, vv, acc[4 * i + 2]);
        acc[4 * i + 3] = fmaf(kk.w, vv, acc[4 * i + 3]);
      }
    }
    if (t < D2_) {
#pragma unroll
      for (int tl = 0; tl < TL_; ++tl) ksacc += ksh[tl][t];
    }
  }

  const size_t base = (size_t)(ch * N_ + n) * D2_ * D_;
#pragma unroll
  for (int i = 0; i < 32; ++i) {
    const int d = g * 32 + i;
    part_kv[base + (size_t)d * D_ + m] = acc[i];
  }
  if (t < D2_) part_ks[(size_t)(ch * N_ + n) * D2_ + t] = ksacc;
}

// ---------------------------------------------------------------------------
// Reduce partials: kv[idx] = sum_ch part_kv[ch][idx]; same for ksum.
// grid: (KV_ELEMS + KS_ELEMS)/256 blocks.
// ---------------------------------------------------------------------------
__global__ __launch_bounds__(256) void reduce_kernel(
    const float* __restrict__ part_kv, const float* __restrict__ part_ks,
    float* __restrict__ kv, float* __restrict__ ks, int chunks) {
  const int idx = blockIdx.x * 256 + threadIdx.x;
  if (idx < KV_ELEMS) {
    float s = 0.f;
    for (int c = 0; c < chunks; ++c) s += part_kv[(size_t)c * KV_ELEMS + idx];
    kv[idx] = s;
  } else {
    const int i2 = idx - KV_ELEMS;
    if (i2 < KS_ELEMS) {
      float s = 0.f;
      for (int c = 0; c < chunks; ++c) s += part_ks[(size_t)c * KS_ELEMS + i2];
      ks[i2] = s;
    }
  }
}

// ---------------------------------------------------------------------------
// Phase 2: out[n,l,m] = (q_ . kv[n])[m] * z,  z = 1/max(q_ . ksum[n], eps)
// grid: 64 heads x 16 l-chunks of 256 = 1024 blocks, 256 threads (4 waves).
// kv staged in LDS as float2 (s-half, c-half interleaved) -> ds_read_b64.
// ---------------------------------------------------------------------------
__global__ __launch_bounds__(256) void phase2_kernel(
    const float* __restrict__ q, const float* __restrict__ kv,
    const float* __restrict__ ks, float* __restrict__ out) {
  __shared__ float kvp[D_ * D_ * 2];  // [(j*64+m)*2 + half] 32KB
  __shared__ float ks2[D2_];          // [2*j + half]

  const int bid = blockIdx.x;
  const int n = bid & 63;
  const int lc = bid >> 6;  // 0..15
  const int b = n >> 4;
  const int h = n & 15;
  const int t = threadIdx.x;

#pragma unroll
  for (int r = 0; r < 32; ++r) {
    const int idx = t + 256 * r;
    const int d = idx >> 6;
    const int m = idx & 63;
    const float val = kv[(size_t)(n * D2_ + d) * D_ + m];
    const int j = d & 63;
    const int half = d >> 6;
    kvp[(j * 64 + m) * 2 + half] = val;
  }
  if (t < D2_) {
    const float val = ks[n * D2_ + t];
    ks2[2 * (t & 63) + (t >> 6)] = val;
  }
  __syncthreads();

  const int wave = t >> 6;
  const int lane = t & 63;
  const int l0 = lc * 256 + wave * 64;
  const float angscale = 0.5f * (float)M_PI / (float)L_;
  const float2* kv2 = (const float2*)kvp;
  const float2 kse = ((const float2*)ks2)[lane];

  for (int il = 0; il < 64; ++il) {
    const int l = l0 + il;
    float ql = q[(size_t)(b * L_ + l) * E_ + h * 64 + lane];
    ql = fmaxf(ql, 0.f);
    const float ang = (float)(l + 1) * angscale;
    const float s = __sinf(ang);
    const float c = __cosf(ang);

    // normalizer: z = 1 / max(q_ . ksum, eps)
    float zp = ql * fmaf(c, kse.y, s * kse.x);
#pragma unroll
    for (int off = 32; off; off >>= 1) zp += __shfl_xor(zp, off);
    const float z = 1.f / fmaxf(zp, EPS_);

    float acc1 = 0.f, acc2 = 0.f;
#pragma unroll
    for (int j = 0; j < 64; ++j) {
      const float qj = __uint_as_float(
          __builtin_amdgcn_readlane(__float_as_uint(ql), j));
      const float2 kk = kv2[j * 64 + lane];
      acc1 = fmaf(qj, kk.x, acc1);
      acc2 = fmaf(qj, kk.y, acc2);
    }
    out[(size_t)(n * L_ + l) * D_ + lane] = fmaf(c, acc2, s * acc1) * z;
  }
}

// ---------------------------------------------------------------------------
extern "C" void kernel_launch(void* const* d_in, const int* in_sizes, int n_in,
                              void* d_out, int out_size, void* d_ws,
                              size_t ws_size, hipStream_t stream) {
  const float* q = (const float*)d_in[0];
  const float* k = (const float*)d_in[1];
  const float* v = (const float*)d_in[2];
  const float* mask = (const float*)d_in[3];
  float* out = (float*)d_out;

  // pick chunk count that fits ws
  const size_t avail = ws_size / 4;
  int chunks = 16;
  while (chunks > 1) {
    const size_t need = (size_t)chunks * KV_ELEMS + (size_t)chunks * KS_ELEMS +
                        KV_ELEMS + KS_ELEMS;
    if (need <= avail) break;
    chunks >>= 1;
  }
  const int lchunk = L_ / chunks;

  float* part_kv = (float*)d_ws;
  float* part_ks = part_kv + (size_t)chunks * KV_ELEMS;
  float* kvbuf = part_ks + (size_t)chunks * KS_ELEMS;
  float* ksbuf = kvbuf + KV_ELEMS;

  phase1_kernel<<<dim3(chunks * 64), dim3(256), 0, stream>>>(k, v, mask,
                                                             part_kv, part_ks,
                                                             lchunk);
  reduce_kernel<<<dim3((KV_ELEMS + KS_ELEMS) / 256), dim3(256), 0, stream>>>(
      part_kv, part_ks, kvbuf, ksbuf, chunks);
  phase2_kernel<<<dim3(16 * 64), dim3(256), 0, stream>>>(q, kvbuf, ksbuf, out);
}

// Round 2
// 247.054 us; speedup vs baseline: 2.0942x; 2.0942x over previous
//
#include <hip/hip_runtime.h>
#include <hip/hip_bf16.h>
#include <math.h>

// Problem constants
#define B_ 4
#define L_ 4096
#define E_ 1024
#define H_ 16
#define D_ 64
#define N_ 64          // B*H heads
#define D2_ 128        // feature dim 2*D
#define EPS_ 1e-6f

#define CH_ 16             // phase1 L-chunks (4 blocks/CU)
#define LC_ (L_ / CH_)     // 256 rows per phase1 block
#define LT_ 64             // rows per LDS stage

typedef short short8 __attribute__((ext_vector_type(8)));
typedef float f32x4 __attribute__((ext_vector_type(4)));
typedef unsigned int u32;
typedef unsigned short u16;

static __device__ __forceinline__ u32 pack2bf(float a, float b) {
  union { __hip_bfloat16 h; u16 s; } x, y;
  x.h = __float2bfloat16(a);
  y.h = __float2bfloat16(b);
  return (u32)x.s | ((u32)y.s << 16);
}

// ---------------------------------------------------------------------------
// Phase 1 (MFMA): partial kv[d][m] = sum_l k_[l][d] * v[l][m], ksum[d]=sum k_
// A = k_^T (LDS ka[d][l], l contiguous), B = v (LDS vt[m][l], l contiguous).
// grid: CH_*64 blocks, 256 thr (4 waves). wave w owns d-rows [32w,32w+32).
// Rows padded to 72 bf16 (=144B, 16B-aligned): frag reads & staging writes
// land at <=2-way bank aliasing (free).
// ---------------------------------------------------------------------------
__global__ __launch_bounds__(256, 4) void phase1_mfma(
    const float* __restrict__ k, const float* __restrict__ v,
    const float* __restrict__ mask,
    float* __restrict__ part_kv, float* __restrict__ part_ks) {
  __shared__ __align__(16) u16 ka[D2_ * 72];
  __shared__ __align__(16) u16 vt[D_ * 72];
  __shared__ float msh[LT_], ssh[LT_], csh[LT_];

  const int bid = blockIdx.x;
  const int n = bid & 63;
  const int ch = bid >> 6;
  const int b = n >> 4;
  const int h = n & 15;
  const int t = threadIdx.x;
  const int wv = t >> 6;
  const int lane = t & 63;
  const int c_lo = lane & 15;
  const int lp = lane >> 4;       // quad
  const int c = wv * 16 + c_lo;   // staging column 0..63

  f32x4 acc[2][4];
#pragma unroll
  for (int i = 0; i < 2; ++i)
#pragma unroll
    for (int j = 0; j < 4; ++j) acc[i][j] = (f32x4)0.f;
  float kss = 0.f, ksc = 0.f;

  const float angscale = 0.5f * 3.14159265358979f / (float)L_;

  for (int st = 0; st < LC_ / LT_; ++st) {
    const int l0 = ch * LC_ + st * LT_;
    __syncthreads();  // protect LDS from previous stage's MFMA readers
    if (t < LT_) {
      const int gl = l0 + t;
      msh[t] = mask[b * L_ + gl];
      const float ang = (float)(gl + 1) * angscale;
      ssh[t] = __sinf(ang);
      csh[t] = __cosf(ang);
    }
    __syncthreads();
    // staging: 64 l x 64 c; thread handles l-pairs (packed b32 LDS writes)
#pragma unroll
    for (int i = 0; i < 8; ++i) {
      const int l = 8 * i + 2 * lp;  // even local row
      const size_t g0 = (size_t)(b * L_ + l0 + l) * E_ + h * 64 + c;
      const float k0 = k[g0], k1 = k[g0 + E_];
      const float v0 = v[g0], v1 = v[g0 + E_];
      const float m0 = msh[l], m1 = msh[l + 1];
      const float s0 = ssh[l], s1 = ssh[l + 1];
      const float c0 = csh[l], c1 = csh[l + 1];
      const float kr0 = fmaxf(k0, 0.f) * m0;
      const float kr1 = fmaxf(k1, 0.f) * m1;
      const float ks0 = kr0 * s0, ks1 = kr1 * s1;
      const float kc0 = kr0 * c0, kc1 = kr1 * c1;
      const int li = l >> 1;
      ((u32*)ka)[c * 36 + li]        = pack2bf(ks0, ks1);
      ((u32*)ka)[(c + 64) * 36 + li] = pack2bf(kc0, kc1);
      ((u32*)vt)[c * 36 + li]        = pack2bf(v0 * m0, v1 * m1);
      kss += ks0 + ks1;
      ksc += kc0 + kc1;
    }
    __syncthreads();
    // MFMA: 2 K-steps of 32 l
#pragma unroll
    for (int kk = 0; kk < 2; ++kk) {
      const int colo = kk * 32 + lp * 8;
      short8 af[2], bfr[4];
#pragma unroll
      for (int dt = 0; dt < 2; ++dt)
        af[dt] = *(const short8*)&ka[(wv * 32 + dt * 16 + c_lo) * 72 + colo];
#pragma unroll
      for (int mt = 0; mt < 4; ++mt)
        bfr[mt] = *(const short8*)&vt[(mt * 16 + c_lo) * 72 + colo];
#pragma unroll
      for (int dt = 0; dt < 2; ++dt)
#pragma unroll
        for (int mt = 0; mt < 4; ++mt)
          acc[dt][mt] = __builtin_amdgcn_mfma_f32_16x16x32_bf16(
              af[dt], bfr[mt], acc[dt][mt], 0, 0, 0);
    }
  }

  // write partial kv (fp32). C layout: row(d)=quad*4+r, col(m)=lane&15
  const size_t pbase = (size_t)(ch * N_ + n) * (D2_ * D_);
#pragma unroll
  for (int dt = 0; dt < 2; ++dt) {
    const int d = wv * 32 + dt * 16 + lp * 4;
#pragma unroll
    for (int mt = 0; mt < 4; ++mt) {
      const int mcol = mt * 16 + c_lo;
#pragma unroll
      for (int r = 0; r < 4; ++r)
        part_kv[pbase + (size_t)(d + r) * D_ + mcol] = acc[dt][mt][r];
    }
  }
  // ksum partials: reduce over lp groups (lanes +-16, +-32)
  kss += __shfl_xor(kss, 16); kss += __shfl_xor(kss, 32);
  ksc += __shfl_xor(ksc, 16); ksc += __shfl_xor(ksc, 32);
  if (lp == 0) {
    part_ks[(size_t)(ch * N_ + n) * D2_ + c] = kss;
    part_ks[(size_t)(ch * N_ + n) * D2_ + c + 64] = ksc;
  }
}

// ---------------------------------------------------------------------------
// Reduce: sum chunk partials; emit kvT[n][m][d] in bf16 (B-operand layout for
// phase2) and ksum fp32. One block per head.
// ---------------------------------------------------------------------------
__global__ __launch_bounds__(256) void reduce_t(
    const float* __restrict__ part_kv, const float* __restrict__ part_ks,
    u16* __restrict__ kvt, float* __restrict__ ks) {
  __shared__ float kvsh[D2_ * 65];  // [d][m] pad 65
  const int n = blockIdx.x;
  const int t = threadIdx.x;

  for (int e = t; e < D2_ * D_; e += 256) {
    float s = 0.f;
#pragma unroll
    for (int cc = 0; cc < CH_; ++cc)
      s += part_kv[(size_t)(cc * N_ + n) * (D2_ * D_) + e];
    kvsh[(e >> 6) * 65 + (e & 63)] = s;
  }
  if (t < D2_) {
    float s = 0.f;
#pragma unroll
    for (int cc = 0; cc < CH_; ++cc)
      s += part_ks[(size_t)(cc * N_ + n) * D2_ + t];
    ks[n * D2_ + t] = s;
  }
  __syncthreads();
  for (int e = t; e < D2_ * D_; e += 256) {
    const int mcol = e >> 7, d = e & 127;
    union { __hip_bfloat16 h; u16 s; } cv;
    cv.h = __float2bfloat16(kvsh[d * 65 + mcol]);
    kvt[(size_t)n * (D2_ * D_) + (size_t)mcol * D2_ + d] = cv.s;
  }
}

// ---------------------------------------------------------------------------
// Phase 2 (MFMA): out[l][m] = z[l] * sum_d q_[l][d] * kv[d][m]
// A = q_ (LDS qa[l][d], d contiguous, no transpose needed!), B = kvT.
// z via 5th B-tile whose column 0 is ksum: acc5 col0 = q_ . ksum.
// grid: 64 heads x 64 l-chunks of 64 rows. wave w owns l-tile w.
// ---------------------------------------------------------------------------
__global__ __launch_bounds__(256, 4) void phase2_mfma(
    const float* __restrict__ q, const u16* __restrict__ kvt,
    const float* __restrict__ ks, float* __restrict__ out) {
  __shared__ __align__(16) u16 qa[64 * 136];
  __shared__ __align__(16) u16 kb[64 * 136];
  __shared__ __align__(16) u16 ksb[16 * 136];
  __shared__ float ssh[64], csh[64];

  const int bid = blockIdx.x;
  const int n = bid & 63;
  const int lc = bid >> 6;
  const int b = n >> 4, h = n & 15;
  const int t = threadIdx.x;
  const int wv = t >> 6, lane = t & 63;
  const int c_lo = lane & 15, quad = lane >> 4;
  const int l0 = lc * 64;

  if (t < 64) {
    const int gl = l0 + t;
    const float ang = (float)(gl + 1) * (0.5f * 3.14159265358979f / (float)L_);
    ssh[t] = __sinf(ang);
    csh[t] = __cosf(ang);
  }
  // ksb: row 0 = ksum (bf16 pairs), rows 1..15 = 0
  if (t < 68)
    ((u32*)ksb)[t] = (t < 64) ? pack2bf(ks[n * D2_ + 2 * t], ks[n * D2_ + 2 * t + 1]) : 0u;
  for (int i = 68 + t; i < 16 * 68; i += 256) ((u32*)ksb)[i] = 0u;
  // kb: straight copy of kvT head (already [m][d] bf16)
  {
    const u32* kv32 = (const u32*)(kvt + (size_t)n * (D2_ * D_));
#pragma unroll
    for (int i = 0; i < 16; ++i) {
      const int idx = t + 256 * i;
      ((u32*)kb)[(idx >> 6) * 68 + (idx & 63)] = kv32[idx];
    }
  }
  __syncthreads();  // ssh ready for q staging

  // q staging: 64 l x 64 c, lane=c (coalesced loads, contiguous b16 writes)
#pragma unroll
  for (int i = 0; i < 16; ++i) {
    const int l = wv + 4 * i;
    const int gl = l0 + l;
    float qv = q[(size_t)(b * L_ + gl) * E_ + h * 64 + lane];
    qv = fmaxf(qv, 0.f);
    const float qs = qv * ssh[l], qc = qv * csh[l];
    union { __hip_bfloat16 h; u16 s; } c1, c2;
    c1.h = __float2bfloat16(qs);
    c2.h = __float2bfloat16(qc);
    qa[l * 136 + lane] = c1.s;
    qa[l * 136 + lane + 64] = c2.s;
  }
  __syncthreads();

  f32x4 acc[4], acc5;
#pragma unroll
  for (int mt = 0; mt < 4; ++mt) acc[mt] = (f32x4)0.f;
  acc5 = (f32x4)0.f;

#pragma unroll
  for (int kk = 0; kk < 4; ++kk) {  // K = 128 = 4 x 32
    const int colo = kk * 32 + quad * 8;
    const short8 af = *(const short8*)&qa[(wv * 16 + c_lo) * 136 + colo];
#pragma unroll
    for (int mt = 0; mt < 4; ++mt) {
      const short8 bfr = *(const short8*)&kb[(mt * 16 + c_lo) * 136 + colo];
      acc[mt] = __builtin_amdgcn_mfma_f32_16x16x32_bf16(af, bfr, acc[mt], 0, 0, 0);
    }
    const short8 bks = *(const short8*)&ksb[c_lo * 136 + colo];
    acc5 = __builtin_amdgcn_mfma_f32_16x16x32_bf16(af, bks, acc5, 0, 0, 0);
  }

  // epilogue: z from acc5 col 0 (lane quad*16), scale, store
#pragma unroll
  for (int r = 0; r < 4; ++r) {
    const float den = __shfl(acc5[r], quad * 16);
    const float z = 1.f / fmaxf(den, EPS_);
    const int gl = l0 + wv * 16 + quad * 4 + r;
    const size_t ob = (size_t)n * (L_ * D_) + (size_t)gl * D_;
#pragma unroll
    for (int mt = 0; mt < 4; ++mt)
      out[ob + mt * 16 + c_lo] = acc[mt][r] * z;
  }
}

// ---------------------------------------------------------------------------
extern "C" void kernel_launch(void* const* d_in, const int* in_sizes, int n_in,
                              void* d_out, int out_size, void* d_ws,
                              size_t ws_size, hipStream_t stream) {
  const float* q = (const float*)d_in[0];
  const float* k = (const float*)d_in[1];
  const float* v = (const float*)d_in[2];
  const float* mask = (const float*)d_in[3];
  float* out = (float*)d_out;

  float* part_kv = (float*)d_ws;                             // 16*64*8192 f32 = 32 MB
  float* part_ks = part_kv + (size_t)CH_ * N_ * D2_ * D_;    // 16*64*128 f32
  u16* kvt = (u16*)(part_ks + (size_t)CH_ * N_ * D2_);       // 64*8192 bf16 = 1 MB
  float* ks = (float*)(kvt + (size_t)N_ * D2_ * D_);         // 64*128 f32

  phase1_mfma<<<dim3(CH_ * N_), dim3(256), 0, stream>>>(k, v, mask, part_kv, part_ks);
  reduce_t<<<dim3(N_), dim3(256), 0, stream>>>(part_kv, part_ks, kvt, ks);
  phase2_mfma<<<dim3(N_ * 64), dim3(256), 0, stream>>>(q, kvt, ks, out);
}